// Round 8
// baseline (98.183 us; speedup 1.0000x reference)
//
#include <hip/hip_runtime.h>
#include <hip/hip_bf16.h>
#include <math.h>

#define B_    2
#define L_    4096
#define H_    8
#define E_    64
#define VTSTR 200        // u16 stride: 400B rows -> 100 dw == 4 mod 32 (2-way max = free)
#define PSTR  72         // u16 stride for wave-private P rows (144B, 16B-aligned)

using frag8 = __attribute__((ext_vector_type(8))) short;  // 8 x bf16 (4 VGPRs)
using fl4   = __attribute__((ext_vector_type(4))) float;  // MFMA C/D / raw vec4 loads

__device__ __forceinline__ unsigned short f2bf(float f) {
    return __builtin_bit_cast(unsigned short, __float2bfloat16(f));
}
__device__ __forceinline__ frag8 pack8v(fl4 a, fl4 b) {
    frag8 r;
    r[0] = (short)f2bf(a.x); r[1] = (short)f2bf(a.y);
    r[2] = (short)f2bf(a.z); r[3] = (short)f2bf(a.w);
    r[4] = (short)f2bf(b.x); r[5] = (short)f2bf(b.y);
    r[6] = (short)f2bf(b.z); r[7] = (short)f2bf(b.w);
    return r;
}

__global__ __launch_bounds__(512, 2)
void lda_kernel(const float* __restrict__ Q, const float* __restrict__ K,
                const float* __restrict__ V, float* __restrict__ O) {
    // TILE = 128 queries/block, 8 waves: wave = (t = lhat-tile 0..3, p = parity)
    __shared__ unsigned short Vt[E_ * VTSTR];        // 25600 B (V^T, [e][p*96 + rhat])
    __shared__ unsigned short Pw[8 * 16 * PSTR];     // 18432 B -> 44032 B total

    const int tid  = threadIdx.x;
    const int lane = tid & 63;
    const int wave = tid >> 6;       // 0..7
    const int col  = lane & 15;
    const int quad = lane >> 4;
    const int p    = wave & 1;       // query parity this wave owns
    const int t    = wave >> 1;      // lhat tile 0..3: lhat in [16t, 16t+16)

    // XCD-aware remap: xcd = g&7 (HW round-robin); 4 consecutive l-tiles x 16 bh per XCD
    const int g   = blockIdx.x;      // 0..511
    const int xcd = g & 7;
    const int s   = g >> 3;          // 0..63
    const int bh  = s & 15;
    const int xt  = (xcd << 2) | (s >> 4);   // l-tile 0..31
    const int l0  = xt * 128;
    const int b   = bh >> 3;
    const int h   = bh & 7;

    const size_t base = ((size_t)(b * L_) * H_ + h) * E_;
    const int    rs   = H_ * E_;     // 512 floats per l-step

    // ---- 1) Q A-frags direct from global, nontemporal (single-use; keep L2 for K/V) ----
    const int lq = l0 + 2 * (16 * t + col) + p;
    frag8 aq[2];
    #pragma unroll
    for (int k = 0; k < 2; ++k) {
        const float* qp = Q + base + (size_t)lq * rs + k * 32 + quad * 8;
        fl4 qa = __builtin_nontemporal_load((const fl4*)qp);
        fl4 qb = __builtin_nontemporal_load((const fl4*)qp + 1);
        aq[k] = pack8v(qa, qb);
    }

    // ---- 2) scores: 3 rhat-tiles, band rhat in [16t, 16t+48) ----
    fl4 S[3];
    #pragma unroll
    for (int c = 0; c < 3; ++c) {
        int rhat = 16 * (t + c) + col;           // 0..95
        int rg = l0 - 32 + 2 * rhat + p;
        rg = rg < 0 ? 0 : (rg > L_ - 1 ? L_ - 1 : rg);
        const float* kp = K + base + (size_t)rg * rs;
        fl4 acc = {0.f, 0.f, 0.f, 0.f};
        #pragma unroll
        for (int k = 0; k < 2; ++k) {
            frag8 bk = pack8v(*(const fl4*)(kp + k * 32 + quad * 8),
                              *(const fl4*)(kp + k * 32 + quad * 8 + 4));
            acc = __builtin_amdgcn_mfma_f32_16x16x32_bf16(aq[k], bk, acc, 0, 0, 0);
        }
        S[c] = acc;
    }

    // ---- 3) V loads issued now (24 scalars), held in regs; latency overlapped ----
    float va[24];
    #pragma unroll
    for (int i = 0; i < 6; ++i) {
        int gi  = wave * 6 + i;       // 0..47
        int pg  = gi / 24;            // staged-row parity
        int rm  = gi - pg * 24;
        int rh0 = rm * 4;             // rhat base 0..92
        #pragma unroll
        for (int j = 0; j < 4; ++j) {
            int rg = l0 - 32 + 2 * (rh0 + j) + pg;
            rg = rg < 0 ? 0 : (rg > L_ - 1 ? L_ - 1 : rg);
            va[i * 4 + j] = V[base + (size_t)rg * rs + lane];
        }
    }

    // ---- 4) unnormalized weights (no max-sub, no cross-lane) ----
    float pw[3][4];
    #pragma unroll
    for (int c = 0; c < 3; ++c)
        #pragma unroll
        for (int reg = 0; reg < 4; ++reg)
            pw[c][reg] = exp2f(S[c][reg] * 0.18033688011112043f);  // 0.125*log2(e)

    // ---- 5) zero + scatter P (wave-private; columns rebased to rb = 32*(t>>1)) ----
    // Aligned 64-wide k-window [rb, rb+64) contains band [16t, 16t+48) for all t,
    // and keeps PV B-frag reads within Vt's 96 rhat (no 0*NaN poison from stale LDS).
    const int pb = wave * 16 * PSTR;
    const int lb = 16 * (t & 1);                 // band start - rb
    #pragma unroll
    for (int i = 0; i < 3; ++i) {
        int idx = lane + 64 * i;
        if (idx < 144) { uint4 z = {0u,0u,0u,0u}; *(uint4*)&Pw[pb + idx * 8] = z; }
    }
    #pragma unroll
    for (int reg = 0; reg < 4; ++reg) {
        int off = quad * 4 + reg;                // lhat local offset
        #pragma unroll
        for (int c = 0; c < 3; ++c) {
            int j = 16 * c + col - off;          // tap index 0..32
            if (j >= 0 && j <= 32)
                Pw[pb + off * PSTR + lb + 16 * c + col] = f2bf(pw[c][reg]);
        }
    }

    // ---- 6) P A-frags + row sums via ones-MFMA ----
    frag8 ap[2];
    #pragma unroll
    for (int k = 0; k < 2; ++k)
        ap[k] = *(const frag8*)&Pw[pb + col * PSTR + k * 32 + quad * 8];

    frag8 ones;
    #pragma unroll
    for (int i = 0; i < 8; ++i) ones[i] = (short)0x3F80;   // bf16 1.0
    fl4 sums = {0.f, 0.f, 0.f, 0.f};
    sums = __builtin_amdgcn_mfma_f32_16x16x32_bf16(ap[0], ones, sums, 0, 0, 0);
    sums = __builtin_amdgcn_mfma_f32_16x16x32_bf16(ap[1], ones, sums, 0, 0, 0);
    float inv[4];
    #pragma unroll
    for (int reg = 0; reg < 4; ++reg) inv[reg] = __builtin_amdgcn_rcpf(sums[reg]);

    // ---- 7) V pack + LDS transpose write ----
    #pragma unroll
    for (int i = 0; i < 6; ++i) {
        int gi  = wave * 6 + i;
        int pg  = gi / 24;
        int rm  = gi - pg * 24;
        int rh0 = rm * 4;
        uint2 u;
        u.x = (unsigned)f2bf(va[i*4+0]) | ((unsigned)f2bf(va[i*4+1]) << 16);
        u.y = (unsigned)f2bf(va[i*4+2]) | ((unsigned)f2bf(va[i*4+3]) << 16);
        *(uint2*)&Vt[lane * VTSTR + pg * 96 + rh0] = u;   // e = lane
    }
    __syncthreads();   // the ONE barrier: Vt ready

    // ---- 8) PV MFMA: k-window [rb, rb+64); O = (1/s_l) * P x V ----
    const int rb = 32 * (t >> 1);
    #pragma unroll
    for (int nt = 0; nt < 4; ++nt) {
        fl4 c = {0.f, 0.f, 0.f, 0.f};
        #pragma unroll
        for (int k = 0; k < 2; ++k) {
            frag8 bv = *(const frag8*)&Vt[(nt * 16 + col) * VTSTR + p * 96 + rb + k * 32 + quad * 8];
            c = __builtin_amdgcn_mfma_f32_16x16x32_bf16(ap[k], bv, c, 0, 0, 0);
        }
        #pragma unroll
        for (int reg = 0; reg < 4; ++reg) {
            int l = l0 + 2 * (16 * t + quad * 4 + reg) + p;
            __builtin_nontemporal_store(c[reg] * inv[reg],
                O + base + (size_t)l * rs + nt * 16 + col);
        }
    }
}

extern "C" void kernel_launch(void* const* d_in, const int* in_sizes, int n_in,
                              void* d_out, int out_size, void* d_ws, size_t ws_size,
                              hipStream_t stream) {
    const float* Q = (const float*)d_in[0];
    const float* K = (const float*)d_in[1];
    const float* V = (const float*)d_in[2];
    float* O = (float*)d_out;

    dim3 grid(L_ / 128 * B_ * H_);   // 512 blocks, 1-D; XCD decomposition inside kernel
    dim3 block(512);
    lda_kernel<<<grid, block, 0, stream>>>(Q, K, V, O);
}